// Round 3
// baseline (14362.094 us; speedup 1.0000x reference)
//
#include <hip/hip_runtime.h>
#include <hip/hip_bf16.h>
#include <stdint.h>

#define TT 2048
#define BB 32
#define II 256
#define HH 256
#define NG 16          // workgroups
#define HW 16          // h-dims per workgroup (HH/NG)
#define MAGICF 0x13572468u

typedef __attribute__((ext_vector_type(8))) short short8;
typedef __attribute__((ext_vector_type(4))) float floatx4;

__device__ __forceinline__ short bf16r(float f) {
    __hip_bfloat16 b = __float2bfloat16(f);
    return *reinterpret_cast<short*>(&b);
}

// 16 WGs x 256 threads. WG w owns h-dims [w*16, w*16+16) -> gate cols
// {g*256 + w*16 + j}. Wave wid (=gate) holds stationary W B-fragments in
// VGPRs (fp32 -> bf16 once). h_t broadcast via d_out (ys[t] IS h_t, fp32);
// flags in d_ws (zeroed by kernel_launch each call).
__global__ __launch_bounds__(256, 1)
void rev_lstm_kernel(const float* __restrict__ x,
                     const float* __restrict__ h0,
                     const float* __restrict__ c0,
                     const float* __restrict__ Wih,
                     const float* __restrict__ Whh,
                     const float* __restrict__ bih,
                     const float* __restrict__ bhh,
                     float* __restrict__ out,
                     unsigned int* __restrict__ flags)
{
    // h staged [b][k] bf16, row stride 272 shorts (544B, 16B aligned)
    __shared__ short h_lds[BB * 272];
    __shared__ float gates_lds[4 * BB * HW];   // [gate][b][j]

    const int w    = blockIdx.x;      // 0..15
    const int tid  = threadIdx.x;     // 0..255
    const int wid  = tid >> 6;        // wave id == gate id (i,f,g,o)
    const int lane = tid & 63;
    const int l15  = lane & 15;
    const int quad = lane >> 4;       // 0..3

    // ---- stationary weight B-fragments (B[k][n]: n=lane&15 -> col, k=quad*8+j)
    const int col = wid * HH + w * HW + l15;          // gate column in [0,1024)
    short8 wihf[8], whhf[8];
#pragma unroll
    for (int kt = 0; kt < 8; ++kt) {
        const int k0 = kt * 32 + quad * 8;
        const float* pi = Wih + (size_t)col * II + k0;
        const float* ph = Whh + (size_t)col * HH + k0;
        short8 a, b;
#pragma unroll
        for (int j = 0; j < 8; ++j) { a[j] = bf16r(pi[j]); b[j] = bf16r(ph[j]); }
        wihf[kt] = a; whhf[kt] = b;
    }
    const float bias = bih[col] + bhh[col];

    // ---- c state fp32 in registers; thread owns (b=jb, j=jj) and (b=jb+16, j=jj)
    const int jb = tid >> 4;   // 0..15
    const int jj = tid & 15;   // 0..15
    float creg0 = c0[(size_t)jb * HH + w * HW + jj];
    float creg1 = c0[(size_t)(jb + 16) * HH + w * HW + jj];

    // ---- prefill h_lds with h0 (fp32 -> bf16)
    {
        const int b = tid >> 3, seg = tid & 7;
        const float* src = h0 + (size_t)b * HH + seg * 32;
#pragma unroll
        for (int u = 0; u < 32; ++u) h_lds[b * 272 + seg * 32 + u] = bf16r(src[u]);
    }
    __syncthreads();

    for (int t = TT - 1; t >= 0; --t) {
        // ---- 1. load this step's x tile (fp32) and convert to bf16 A-fragments
        short8 xa0[8], xa1[8];
        const float* xt = x + (size_t)t * (BB * II);
#pragma unroll
        for (int kt = 0; kt < 8; ++kt) {
            const int k0 = kt * 32 + quad * 8;
            const float4 u0 = *reinterpret_cast<const float4*>(xt + (size_t)l15 * II + k0);
            const float4 u1 = *reinterpret_cast<const float4*>(xt + (size_t)l15 * II + k0 + 4);
            const float4 v0 = *reinterpret_cast<const float4*>(xt + (size_t)(l15 + 16) * II + k0);
            const float4 v1 = *reinterpret_cast<const float4*>(xt + (size_t)(l15 + 16) * II + k0 + 4);
            short8 a, b;
            a[0]=bf16r(u0.x); a[1]=bf16r(u0.y); a[2]=bf16r(u0.z); a[3]=bf16r(u0.w);
            a[4]=bf16r(u1.x); a[5]=bf16r(u1.y); a[6]=bf16r(u1.z); a[7]=bf16r(u1.w);
            b[0]=bf16r(v0.x); b[1]=bf16r(v0.y); b[2]=bf16r(v0.z); b[3]=bf16r(v0.w);
            b[4]=bf16r(v1.x); b[5]=bf16r(v1.y); b[6]=bf16r(v1.z); b[7]=bf16r(v1.w);
            xa0[kt] = a; xa1[kt] = b;
        }

        // ---- 2. wait for h_{t+1} from all 16 producers, then gather into LDS
        if (t != TT - 1) {
            if (tid < NG) {
                unsigned int* f = flags + (size_t)(t + 1) * NG + tid;
                unsigned spins = 0;
                while (__hip_atomic_load(f, __ATOMIC_RELAXED, __HIP_MEMORY_SCOPE_AGENT) != MAGICF) {
                    if (++spins > 2000000u) break;   // fail loud, never hang
                }
            }
            __syncthreads();
            __builtin_amdgcn_fence(__ATOMIC_ACQUIRE, "agent");   // inv caches
            const float* hsrc = out + (size_t)(t + 1) * (BB * HH);
            const int b = tid >> 3, seg = tid & 7;
            const float* src = hsrc + (size_t)b * HH + seg * 32;
            short hv[32];
#pragma unroll
            for (int q = 0; q < 8; ++q) {
                const float4 v = *reinterpret_cast<const float4*>(src + q * 4);
                hv[q*4+0] = bf16r(v.x); hv[q*4+1] = bf16r(v.y);
                hv[q*4+2] = bf16r(v.z); hv[q*4+3] = bf16r(v.w);
            }
            uint4* dst = reinterpret_cast<uint4*>(h_lds + b * 272 + seg * 32);
            const uint4* hv4 = reinterpret_cast<const uint4*>(hv);
            dst[0] = hv4[0]; dst[1] = hv4[1]; dst[2] = hv4[2]; dst[3] = hv4[3];
            __syncthreads();
        }

        // ---- 3. MFMA: gates[32, 64-slice] = x_t@Wihᵀ + h@Whhᵀ + bias
        floatx4 acc0 = {bias, bias, bias, bias};
        floatx4 acc1 = {bias, bias, bias, bias};
#pragma unroll
        for (int kt = 0; kt < 8; ++kt) {
            acc0 = __builtin_amdgcn_mfma_f32_16x16x32_bf16(xa0[kt], wihf[kt], acc0, 0, 0, 0);
            acc1 = __builtin_amdgcn_mfma_f32_16x16x32_bf16(xa1[kt], wihf[kt], acc1, 0, 0, 0);
        }
#pragma unroll
        for (int kt = 0; kt < 8; ++kt) {
            const int off = kt * 32 + quad * 8;
            short8 ha0 = *reinterpret_cast<const short8*>(h_lds + l15 * 272 + off);
            short8 ha1 = *reinterpret_cast<const short8*>(h_lds + (l15 + 16) * 272 + off);
            acc0 = __builtin_amdgcn_mfma_f32_16x16x32_bf16(ha0, whhf[kt], acc0, 0, 0, 0);
            acc1 = __builtin_amdgcn_mfma_f32_16x16x32_bf16(ha1, whhf[kt], acc1, 0, 0, 0);
        }

        // ---- 4. accumulators -> LDS (C/D layout: col=lane&15, row=quad*4+r)
#pragma unroll
        for (int r = 0; r < 4; ++r) {
            gates_lds[(wid * BB + quad * 4 + r) * HW + l15]      = acc0[r];
            gates_lds[(wid * BB + 16 + quad * 4 + r) * HW + l15] = acc1[r];
        }
        __syncthreads();

        // ---- 5. elementwise LSTM cell; h -> ys[t] (fp32, doubles as broadcast)
#pragma unroll
        for (int n = 0; n < 2; ++n) {
            const int b = jb + n * 16;
            const float ig = gates_lds[(0 * BB + b) * HW + jj];
            const float fg = gates_lds[(1 * BB + b) * HW + jj];
            const float gg = gates_lds[(2 * BB + b) * HW + jj];
            const float og = gates_lds[(3 * BB + b) * HW + jj];
            const float is = 1.f / (1.f + __expf(-ig));
            const float fs = 1.f / (1.f + __expf(-fg));
            const float gt = 1.f - 2.f / (1.f + __expf(2.f * gg));
            const float os = 1.f / (1.f + __expf(-og));
            const float cprev = (n == 0) ? creg0 : creg1;
            const float c  = fs * cprev + is * gt;
            const float h  = os * (1.f - 2.f / (1.f + __expf(2.f * c)));
            if (n == 0) creg0 = c; else creg1 = c;
            out[(size_t)t * (BB * HH) + (size_t)b * HH + w * HW + jj] = h;
            if (t == 0) {
                // hT = ys[0]; cT follows hT
                out[(size_t)TT * (BB * HH) + (size_t)b * HH + w * HW + jj] = h;
                out[(size_t)TT * (BB * HH) + (BB * HH) + (size_t)b * HH + w * HW + jj] = c;
            }
        }
        // __syncthreads drains vmcnt(0) before s_barrier -> all WG h-stores at L2;
        // tid0's release fence (wbl2) pushes them to LLC before the flag.
        __syncthreads();
        if (tid == 0) {
            __builtin_amdgcn_fence(__ATOMIC_RELEASE, "agent");
            __hip_atomic_store(flags + (size_t)t * NG + w, MAGICF,
                               __ATOMIC_RELAXED, __HIP_MEMORY_SCOPE_AGENT);
        }
    }
}

extern "C" void kernel_launch(void* const* d_in, const int* in_sizes, int n_in,
                              void* d_out, int out_size, void* d_ws, size_t ws_size,
                              hipStream_t stream) {
    const float* x   = (const float*)d_in[0];
    const float* h0  = (const float*)d_in[1];
    const float* c0  = (const float*)d_in[2];
    const float* Wih = (const float*)d_in[3];
    const float* Whh = (const float*)d_in[4];
    const float* bih = (const float*)d_in[5];
    const float* bhh = (const float*)d_in[6];
    float* out = (float*)d_out;
    unsigned int* flags = (unsigned int*)d_ws;   // 2048*16*4 = 128 KB

    hipMemsetAsync(flags, 0, (size_t)TT * NG * sizeof(unsigned int), stream);
    hipLaunchKernelGGL(rev_lstm_kernel, dim3(NG), dim3(256), 0, stream,
                       x, h0, c0, Wih, Whh, bih, bhh, out, flags);
}